// Round 1
// baseline (422.823 us; speedup 1.0000x reference)
//
#include <hip/hip_runtime.h>
#include <math.h>

#define NN 8192
#define IN_DIM 64
#define OUT_DIM 64
#define HEADS 2
#define GAT_EPS 1e-10f

// ---------------------------------------------------------------------------
// Kernel 1: ft[n][j] = features[n][:] . W_lin[j][:] + b_lin[j]   (j = h*64+c)
// One thread per output element. features row is wave-uniform (broadcast);
// W_lin (32 KB) stays hot in L1/L2. Total 134 MFLOP -> ~1-2 us.
// ---------------------------------------------------------------------------
__global__ void ft_kernel(const float* __restrict__ features,
                          const float* __restrict__ W_lin,
                          const float* __restrict__ b_lin,
                          float* __restrict__ ft) {
    int gid = blockIdx.x * blockDim.x + threadIdx.x;   // n*128 + j
    int n = gid >> 7;
    int j = gid & 127;
    const float4* f4 = (const float4*)(features + (size_t)n * IN_DIM);
    const float4* w4 = (const float4*)(W_lin + (size_t)j * IN_DIM);
    float acc = 0.f;
#pragma unroll
    for (int d = 0; d < IN_DIM / 4; ++d) {
        float4 a = f4[d];
        float4 b = w4[d];
        acc += a.x * b.x + a.y * b.y + a.z * b.z + a.w * b.w;
    }
    ft[gid] = acc + b_lin[j];
}

// ---------------------------------------------------------------------------
// Kernel 2: per-node score factors.
//   r[n][h]  = exp(features[n].W_attn[h][:64] + b_attn[h])   (row factor)
//   pd[n][h] = exp(features[n].W_attn[h][64:])               (column factor)
// score[n,h,m] = r[n][h] * pd[m][h] * adj_sl[n,m]
// ---------------------------------------------------------------------------
__global__ void score_kernel(const float* __restrict__ features,
                             const float* __restrict__ W_attn,
                             const float* __restrict__ b_attn,
                             float* __restrict__ r,
                             float* __restrict__ pd) {
    int n = blockIdx.x * blockDim.x + threadIdx.x;
    const float4* f4  = (const float4*)(features + (size_t)n * IN_DIM);
    const float4* wa0 = (const float4*)(W_attn);            // head 0, 128 floats
    const float4* wa1 = (const float4*)(W_attn + 2 * IN_DIM); // head 1
    float s00 = 0.f, s01 = 0.f, s10 = 0.f, s11 = 0.f;
#pragma unroll
    for (int d = 0; d < IN_DIM / 4; ++d) {
        float4 f = f4[d];
        float4 a = wa0[d];            // h0 src
        float4 b = wa0[16 + d];       // h0 dst
        float4 c = wa1[d];            // h1 src
        float4 e = wa1[16 + d];       // h1 dst
        s00 += f.x * a.x + f.y * a.y + f.z * a.z + f.w * a.w;
        s01 += f.x * b.x + f.y * b.y + f.z * b.z + f.w * b.w;
        s10 += f.x * c.x + f.y * c.y + f.z * c.z + f.w * c.w;
        s11 += f.x * e.x + f.y * e.y + f.z * e.z + f.w * e.w;
    }
    r[2 * n]      = __expf(s00 + b_attn[0]);
    r[2 * n + 1]  = __expf(s10 + b_attn[1]);
    pd[2 * n]     = __expf(s01);
    pd[2 * n + 1] = __expf(s11);
}

// ---------------------------------------------------------------------------
// Kernel 3: one wave (64 lanes) per node row n.
// Stream adj row coalesced as float4, ballot nonzeros, shfl-broadcast each
// (m, a) to all lanes. Lane t owns out[n][t] (head0) and out[n][64+t] (head1).
// Single pass accumulates numerator and denominator; divide + ELU epilogue.
// ---------------------------------------------------------------------------
__global__ void gat_agg_kernel(const float* __restrict__ adj,
                               const float* __restrict__ ft,
                               const float* __restrict__ r,
                               const float* __restrict__ pd,
                               float* __restrict__ out) {
    int wave = (blockIdx.x * blockDim.x + threadIdx.x) >> 6;  // node n
    int lane = threadIdx.x & 63;
    int n = wave;

    float r0 = r[2 * n];
    float r1 = r[2 * n + 1];
    float acc0 = 0.f, acc1 = 0.f, den0 = 0.f, den1 = 0.f;

    const float4* arow = (const float4*)(adj + (size_t)n * NN);

#pragma unroll 1
    for (int it = 0; it < NN / (64 * 4); ++it) {   // 32 iterations
        float4 v = arow[it * 64 + lane];
        int base = it * 256 + lane * 4;            // column of v.x
        // self-loop: adj_sl = adj + I  (element [n][n] += 1.0)
        if (base <= n && n < base + 4) {
            ((float*)&v)[n - base] += 1.0f;
        }
#pragma unroll
        for (int k = 0; k < 4; ++k) {
            float vk = ((const float*)&v)[k];
            unsigned long long mask = __ballot(vk != 0.0f);
            while (mask) {
                int src = __ffsll((unsigned long long)mask) - 1;
                mask &= mask - 1;
                float a = __shfl(vk, src);
                int m = it * 256 + src * 4 + k;
                float p0 = pd[2 * m];
                float p1 = pd[2 * m + 1];
                float w0 = r0 * p0 * a;
                float w1 = r1 * p1 * a;
                const float* f = ft + (size_t)m * 128;
                acc0 += w0 * f[lane];
                acc1 += w1 * f[64 + lane];
                den0 += w0;
                den1 += w1;
            }
        }
    }

    float o0 = acc0 / (den0 + GAT_EPS);
    float o1 = acc1 / (den1 + GAT_EPS);
    o0 = o0 > 0.f ? o0 : expm1f(o0);
    o1 = o1 > 0.f ? o1 : expm1f(o1);
    out[(size_t)n * 128 + lane]      = o0;
    out[(size_t)n * 128 + 64 + lane] = o1;
}

extern "C" void kernel_launch(void* const* d_in, const int* in_sizes, int n_in,
                              void* d_out, int out_size, void* d_ws, size_t ws_size,
                              hipStream_t stream) {
    const float* adj      = (const float*)d_in[0];  // [N, N]
    const float* features = (const float*)d_in[1];  // [N, 64]
    const float* W_attn   = (const float*)d_in[2];  // [2, 128]
    const float* b_attn   = (const float*)d_in[3];  // [2]
    const float* W_lin    = (const float*)d_in[4];  // [128, 64]
    const float* b_lin    = (const float*)d_in[5];  // [128]
    float* out = (float*)d_out;                     // [N, 128]

    float* ws = (float*)d_ws;
    float* ft = ws;                       // N*128 floats = 4 MB
    float* r  = ws + (size_t)NN * 128;    // N*2
    float* pd = r + (size_t)NN * 2;       // N*2

    // Kernel 1: feature transform
    ft_kernel<<<(NN * 128) / 256, 256, 0, stream>>>(features, W_lin, b_lin, ft);
    // Kernel 2: score factors
    score_kernel<<<NN / 256, 256, 0, stream>>>(features, W_attn, b_attn, r, pd);
    // Kernel 3: masked-softmax aggregation, one wave per node
    gat_agg_kernel<<<(NN / 4), 256, 0, stream>>>(adj, ft, r, pd, out);
}